// Round 6
// baseline (195.477 us; speedup 1.0000x reference)
//
#include <hip/hip_runtime.h>
#include <math.h>

#define NUM_TASKS 16
#define B_ROWS    8192
#define P_ROWS    10240            // padded sorted-row space (each task 128-aligned)
#define BM        128
#define MAX_TILES 80

typedef __attribute__((ext_vector_type(4))) float f32x4;
typedef __attribute__((ext_vector_type(8))) short bf16x8;
typedef __attribute__((ext_vector_type(4))) short bf16x4;
typedef unsigned short ushort_t;

__device__ __forceinline__ short f2bf(float f) {
    union { float f; unsigned u; } c; c.f = f;
    unsigned u = c.u;
    unsigned r = (u + 0x7FFFu + ((u >> 16) & 1u)) >> 16;
    return (short)r;
}

// ---------------------------------------------------------------------------
// Fragment-major packed layout (both A-type and B-type operands):
//   elem(m, k; K) = ((m>>4)*(K/8) + (k>>3))*128 + (m&15)*8 + (k&7)
// A wave's MFMA fragment (16 rows x 8 k) is 1KB CONTIGUOUS:
//   lane l reads bytes base + (l>>4)*256 + (l&15)*16.
// ---------------------------------------------------------------------------

// ---------------------------------------------------------------------------
// Bucket kernel: stable counting sort into PADDED positions (task start
// rounded to 128 so every tile is 16-aligned for the packed layout).
// ---------------------------------------------------------------------------
__global__ __launch_bounds__(256) void bucket_kernel(
    const int* __restrict__ task_ids,
    int* __restrict__ sidx,
    int* __restrict__ tile_base,
    int* __restrict__ tile_task,
    int* __restrict__ tile_end,
    int* __restrict__ ntiles)
{
    __shared__ int cnt[256][NUM_TASKS];
    __shared__ int pstart[NUM_TASKS];
    __shared__ int tot[NUM_TASKS];

    const int tid = threadIdx.x;
    #pragma unroll
    for (int t = 0; t < NUM_TASKS; ++t) cnt[tid][t] = 0;
    const int base = tid * (B_ROWS / 256);

    for (int i = 0; i < B_ROWS / 256; ++i) {
        int t = task_ids[base + i];
        cnt[tid][t]++;
    }
    __syncthreads();

    if (tid < NUM_TASKS) {
        int s = 0;
        for (int c = 0; c < 256; ++c) { int v = cnt[c][tid]; cnt[c][tid] = s; s += v; }
        tot[tid] = s;
    }
    __syncthreads();

    if (tid == 0) {
        int p = 0, nt = 0;
        for (int t = 0; t < NUM_TASKS; ++t) {
            pstart[t] = p;
            for (int r = 0; r < tot[t]; r += BM) {
                tile_base[nt] = p + r;
                tile_task[nt] = t;
                tile_end[nt]  = p + tot[t];
                nt++;
            }
            p += ((tot[t] + BM - 1) / BM) * BM;
        }
        *ntiles = nt;
    }
    __syncthreads();

    // zero-init sidx (pad rows -> source row 0, harmless; never written out)
    for (int i = 0; i < P_ROWS / 256; ++i) sidx[tid + i * 256] = 0;
    __syncthreads();

    for (int i = 0; i < B_ROWS / 256; ++i) {
        int row = base + i;
        int t = task_ids[row];
        int pos = pstart[t] + cnt[tid][t];
        cnt[tid][t] = cnt[tid][t] + 1;
        sidx[pos] = row;
    }
}

// ---------------------------------------------------------------------------
// x gather + convert + pack: xs = PA(x[sidx[pos]]) ; K=512. 4 rows/block.
// ---------------------------------------------------------------------------
__global__ __launch_bounds__(256) void xconv(
    const float* __restrict__ x,
    const int* __restrict__ sidx,
    ushort_t* __restrict__ xs)
{
    const int tid  = threadIdx.x;
    const int pos  = blockIdx.x * 4 + (tid >> 6);
    const int lane = tid & 63;
    const int src  = sidx[pos];
    const float* sp = x + (size_t)src * 512 + lane * 8;
    f32x4 v0 = *(const f32x4*)sp;
    f32x4 v1 = *(const f32x4*)(sp + 4);
    bf16x8 pk;
    pk[0] = f2bf(v0[0]); pk[1] = f2bf(v0[1]);
    pk[2] = f2bf(v0[2]); pk[3] = f2bf(v0[3]);
    pk[4] = f2bf(v1[0]); pk[5] = f2bf(v1[1]);
    pk[6] = f2bf(v1[2]); pk[7] = f2bf(v1[3]);
    // packed: k-group = lane, m-group = pos>>4, sub = (pos&15)*8
    ushort_t* dp = xs + ((size_t)(pos >> 4) * 64 + lane) * 128 + (pos & 15) * 8;
    *(bf16x8*)dp = pk;
}

// ---------------------------------------------------------------------------
// Weight convert + transpose + pack: W[t][k][n] fp32 -> PB layout bf16.
// ---------------------------------------------------------------------------
template<int K, int N>
__global__ __launch_bounds__(256) void wconv(
    const float* __restrict__ W, ushort_t* __restrict__ Wt)
{
    const int t  = blockIdx.z;
    const int kb = blockIdx.y * 64;
    const int nb = blockIdx.x * 64;
    const float* src = W + (size_t)t * K * N;
    ushort_t* dst = Wt + (size_t)t * N * K;

    __shared__ ushort_t tile[64][68];

    const int tid = threadIdx.x;
    {
        int kl  = tid >> 4;
        int nl4 = (tid & 15) * 4;
        #pragma unroll
        for (int r = 0; r < 4; ++r) {
            int k = kl + r * 16;
            f32x4 v = *(const f32x4*)(src + (size_t)(kb + k) * N + nb + nl4);
            tile[nl4 + 0][k] = (ushort_t)f2bf(v[0]);
            tile[nl4 + 1][k] = (ushort_t)f2bf(v[1]);
            tile[nl4 + 2][k] = (ushort_t)f2bf(v[2]);
            tile[nl4 + 3][k] = (ushort_t)f2bf(v[3]);
        }
    }
    __syncthreads();
    {
        int nl = tid >> 2;            // 0..63 local n
        int c  = (tid & 3) * 16;      // local k chunk of 16
        int n  = nb + nl;
        int k0 = kb + c;
        bf16x4 v0 = *(const bf16x4*)&tile[nl][c + 0];
        bf16x4 v1 = *(const bf16x4*)&tile[nl][c + 4];
        bf16x4 v2 = *(const bf16x4*)&tile[nl][c + 8];
        bf16x4 v3 = *(const bf16x4*)&tile[nl][c + 12];
        ushort_t* dg = dst + ((size_t)(n >> 4) * (K / 8) + (k0 >> 3)) * 128
                           + (n & 15) * 8;
        *(bf16x4*)(dg + 0)   = v0;
        *(bf16x4*)(dg + 4)   = v1;
        *(bf16x4*)(dg + 128) = v2;
        *(bf16x4*)(dg + 132) = v3;
    }
}

// ---------------------------------------------------------------------------
// Wave-independent GEMM: NO LDS, NO barriers. Each wave owns a 64x64 output
// tile; A/B fragments loaded 1KB-contiguous from packed layout straight into
// VGPRs; depth-1 register double-buffer; K-loop fully unrolled (static regs).
// 4 independent waves per 256-thread block. 12 waves/CU latency hiding.
// ---------------------------------------------------------------------------
template<int K, int N, int OUT_FINAL>
__global__ __launch_bounds__(256, 3) void wave_gemm(
    const ushort_t* __restrict__ in,     // PA packed, P_ROWS x K
    const ushort_t* __restrict__ wt,     // PB packed [T], N x K each
    const float* __restrict__ bias,      // [T][N]
    void* __restrict__ out,
    const int* __restrict__ sidx,
    const int* __restrict__ tile_base,
    const int* __restrict__ tile_task,
    const int* __restrict__ tile_end,
    const int* __restrict__ ntiles)
{
    constexpr int NS  = N / 64;          // n-slices per tile
    constexpr int WPT = 2 * NS;          // waves per 128-row tile
    constexpr int NB  = MAX_TILES * WPT / 4;
    constexpr int NT  = K / 32;

    // bijective XCD swizzle (NB % 8 == 0 for all instantiations)
    const int orig = blockIdx.x;
    constexpr int q = NB / 8;
    const int wgid = (orig & 7) * q + (orig >> 3);

    const int gw   = wgid * 4 + (threadIdx.x >> 6);
    const int tile = gw / WPT;
    const int sub  = gw % WPT;
    const int half = sub / NS;
    const int ns   = sub % NS;

    if (tile >= *ntiles) return;         // per-wave exit; no barriers anywhere
    const int rowbase = tile_base[tile]; // 128-aligned
    const int task    = tile_task[tile];
    const int rowend  = tile_end[tile];

    const int lane = threadIdx.x & 63;
    const int r16  = lane & 15;
    const int loff = (lane >> 4) * 128 + r16 * 8;   // lane's elem offset in frag block

    const int mg0 = (rowbase >> 4) + half * 4;      // A m-group base
    const ushort_t* Ab[4];
    #pragma unroll
    for (int mf = 0; mf < 4; ++mf)
        Ab[mf] = in + ((size_t)(mg0 + mf) * (K / 8)) * 128 + loff;

    const ushort_t* Wtt = wt + (size_t)task * N * K;
    const ushort_t* Bb[4];
    #pragma unroll
    for (int nf = 0; nf < 4; ++nf)
        Bb[nf] = Wtt + ((size_t)(ns * 4 + nf) * (K / 8)) * 128 + loff;

    f32x4 acc[4][4];
    #pragma unroll
    for (int mf = 0; mf < 4; ++mf)
        #pragma unroll
        for (int nf = 0; nf < 4; ++nf)
            acc[mf][nf] = (f32x4){0.f, 0.f, 0.f, 0.f};

    bf16x8 a[2][4], b[2][4];
    #pragma unroll
    for (int mf = 0; mf < 4; ++mf) a[0][mf] = *(const bf16x8*)(Ab[mf]);
    #pragma unroll
    for (int nf = 0; nf < 4; ++nf) b[0][nf] = *(const bf16x8*)(Bb[nf]);

    #pragma unroll
    for (int t = 0; t < NT; ++t) {
        const int cur = t & 1;
        if (t + 1 < NT) {
            const int ke = (t + 1) * 512;            // 512 elems per k32 step
            #pragma unroll
            for (int mf = 0; mf < 4; ++mf)
                a[cur ^ 1][mf] = *(const bf16x8*)(Ab[mf] + ke);
            #pragma unroll
            for (int nf = 0; nf < 4; ++nf)
                b[cur ^ 1][nf] = *(const bf16x8*)(Bb[nf] + ke);
        }
        #pragma unroll
        for (int mf = 0; mf < 4; ++mf)
            #pragma unroll
            for (int nf = 0; nf < 4; ++nf)
                acc[mf][nf] = __builtin_amdgcn_mfma_f32_16x16x32_bf16(
                    a[cur][mf], b[cur][nf], acc[mf][nf], 0, 0, 0);
    }

    // ---- epilogue ----
    const int rg = lane >> 4;
    #pragma unroll
    for (int nf = 0; nf < 4; ++nf) {
        const int col = ns * 64 + nf * 16 + r16;
        const float bv = bias[(size_t)task * N + col];
        #pragma unroll
        for (int mf = 0; mf < 4; ++mf) {
            #pragma unroll
            for (int r = 0; r < 4; ++r) {
                const int m = rowbase + half * 64 + mf * 16 + rg * 4 + r;
                if (m < rowend) {
                    float v = acc[mf][nf][r] + bv;
                    if (!OUT_FINAL) {
                        v = tanhf(v);
                        // write H in PA layout (next layer's A, K_next = N)
                        ushort_t* Hp = (ushort_t*)out;
                        size_t e = ((size_t)(m >> 4) * (N / 8) + (col >> 3)) * 128
                                 + (m & 15) * 8 + (col & 7);
                        Hp[e] = (ushort_t)f2bf(v);
                    } else {
                        ((float*)out)[(size_t)sidx[m] * N + col] = v;
                    }
                }
            }
        }
    }
}

// ---------------------------------------------------------------------------
extern "C" void kernel_launch(void* const* d_in, const int* in_sizes, int n_in,
                              void* d_out, int out_size, void* d_ws, size_t ws_size,
                              hipStream_t stream)
{
    const float* x        = (const float*)d_in[0];
    const int*   task_ids = (const int*)  d_in[1];
    const float* k0       = (const float*)d_in[2];
    const float* b0       = (const float*)d_in[3];
    const float* k1       = (const float*)d_in[4];
    const float* b1       = (const float*)d_in[5];
    const float* k2       = (const float*)d_in[6];
    const float* b2       = (const float*)d_in[7];
    float* out = (float*)d_out;

    char* ws = (char*)d_ws;
    int* sidx      = (int*)ws;                 // P_ROWS ints
    int* tile_base = sidx + P_ROWS;
    int* tile_task = tile_base + 128;
    int* tile_end  = tile_task + 128;
    int* ntiles    = tile_end + 128;

    size_t off = 131072;
    ushort_t* xs  = (ushort_t*)(ws + off); off += (size_t)P_ROWS * 512 * 2;
    ushort_t* H0  = (ushort_t*)(ws + off); off += (size_t)P_ROWS * 1024 * 2;
    ushort_t* H1  = (ushort_t*)(ws + off); off += (size_t)P_ROWS * 1024 * 2;
    ushort_t* Wt0 = (ushort_t*)(ws + off); off += (size_t)16 * 512 * 1024 * 2;
    ushort_t* Wt1 = (ushort_t*)(ws + off); off += (size_t)16 * 1024 * 1024 * 2;
    ushort_t* Wt2 = (ushort_t*)(ws + off); off += (size_t)16 * 1024 * 256 * 2;

    bucket_kernel<<<1, 256, 0, stream>>>(task_ids, sidx, tile_base, tile_task,
                                         tile_end, ntiles);
    xconv<<<P_ROWS / 4, 256, 0, stream>>>(x, sidx, xs);
    wconv< 512, 1024><<<dim3(16,  8, 16), 256, 0, stream>>>(k0, Wt0);
    wconv<1024, 1024><<<dim3(16, 16, 16), 256, 0, stream>>>(k1, Wt1);
    wconv<1024,  256><<<dim3( 4, 16, 16), 256, 0, stream>>>(k2, Wt2);

    // grids: MAX_TILES * (2*N/64) waves / 4 waves-per-block
    wave_gemm< 512, 1024, 0><<<MAX_TILES * 32 / 4, 256, 0, stream>>>(
        xs, Wt0, b0, H0, sidx, tile_base, tile_task, tile_end, ntiles);
    wave_gemm<1024, 1024, 0><<<MAX_TILES * 32 / 4, 256, 0, stream>>>(
        H0, Wt1, b1, H1, sidx, tile_base, tile_task, tile_end, ntiles);
    wave_gemm<1024,  256, 1><<<MAX_TILES *  8 / 4, 256, 0, stream>>>(
        H1, Wt2, b2, out, sidx, tile_base, tile_task, tile_end, ntiles);
}

// Round 7
// 146.005 us; speedup vs baseline: 1.3388x; 1.3388x over previous
//
#include <hip/hip_runtime.h>
#include <math.h>

#define NUM_TASKS 16
#define B_ROWS    8192
#define TROWS     32               // rows per fused tile
#define NB_FUSED  272              // max tiles: 8192/32 + 16
#define P_ROWS    8704             // padded sorted-row space (tasks 32-aligned)

typedef __attribute__((ext_vector_type(4))) float f32x4;
typedef __attribute__((ext_vector_type(8))) short bf16x8;
typedef __attribute__((ext_vector_type(4))) short bf16x4;
typedef unsigned short ushort_t;

__device__ __forceinline__ short f2bf(float f) {
    union { float f; unsigned u; } c; c.f = f;
    unsigned u = c.u;
    unsigned r = (u + 0x7FFFu + ((u >> 16) & 1u)) >> 16;
    return (short)r;
}

__device__ __forceinline__ float fast_tanh(float x) {
    float e = __expf(2.0f * x);
    return 1.0f - 2.0f / (e + 1.0f);   // exact at +-inf, ~1e-7 err mid-range
}

// ---------------------------------------------------------------------------
// Packed fragment-major operand layout for ALL matrices ([X][K], 16-row grps):
//   elem(x, k; K) = ((x>>4)*(K/8) + (k>>3))*128 + (x&15)*8 + (k&7)
// A wave's 16x32 MFMA fragment is 1KB contiguous; lane l reads 16B at
//   (l>>4)*256 + (l&15)*16.
// In LDS the 16B slot is XOR-swizzled by the k-group: slot = (x&15)^(kg&7)
// (write and read apply the same XOR -> conflict-free both directions).
// ---------------------------------------------------------------------------

// ---------------------------------------------------------------------------
// Bucket kernel: stable counting sort of rows by task, tasks padded to 32.
// ---------------------------------------------------------------------------
__global__ __launch_bounds__(256) void bucket_kernel(
    const int* __restrict__ task_ids,
    int* __restrict__ sidx,
    int* __restrict__ tile_base,
    int* __restrict__ tile_task,
    int* __restrict__ tile_end,
    int* __restrict__ ntiles)
{
    __shared__ int cnt[256][NUM_TASKS];
    __shared__ int pstart[NUM_TASKS];
    __shared__ int tot[NUM_TASKS];

    const int tid = threadIdx.x;
    #pragma unroll
    for (int t = 0; t < NUM_TASKS; ++t) cnt[tid][t] = 0;
    const int base = tid * (B_ROWS / 256);

    for (int i = 0; i < B_ROWS / 256; ++i) {
        int t = task_ids[base + i];
        cnt[tid][t]++;
    }
    __syncthreads();

    if (tid < NUM_TASKS) {
        int s = 0;
        for (int c = 0; c < 256; ++c) { int v = cnt[c][tid]; cnt[c][tid] = s; s += v; }
        tot[tid] = s;
    }
    __syncthreads();

    if (tid == 0) {
        int p = 0, nt = 0;
        for (int t = 0; t < NUM_TASKS; ++t) {
            pstart[t] = p;
            for (int r = 0; r < tot[t]; r += TROWS) {
                tile_base[nt] = p + r;
                tile_task[nt] = t;
                tile_end[nt]  = p + tot[t];
                nt++;
            }
            p += ((tot[t] + TROWS - 1) / TROWS) * TROWS;
        }
        *ntiles = nt;
    }
    __syncthreads();

    for (int i = 0; i < P_ROWS / 256; ++i) sidx[tid + i * 256] = 0;
    __syncthreads();

    for (int i = 0; i < B_ROWS / 256; ++i) {
        int row = base + i;
        int t = task_ids[row];
        int pos = pstart[t] + cnt[tid][t];
        cnt[tid][t] = cnt[tid][t] + 1;
        sidx[pos] = row;
    }
}

// ---------------------------------------------------------------------------
// Weight convert + transpose + pack: W[t][k][n] fp32 -> packed [t][n][k] bf16.
// (verified in R6 — unchanged)
// ---------------------------------------------------------------------------
template<int K, int N>
__global__ __launch_bounds__(256) void wconv(
    const float* __restrict__ W, ushort_t* __restrict__ Wt)
{
    const int t  = blockIdx.z;
    const int kb = blockIdx.y * 64;
    const int nb = blockIdx.x * 64;
    const float* src = W + (size_t)t * K * N;
    ushort_t* dst = Wt + (size_t)t * N * K;

    __shared__ ushort_t tile[64][68];

    const int tid = threadIdx.x;
    {
        int kl  = tid >> 4;
        int nl4 = (tid & 15) * 4;
        #pragma unroll
        for (int r = 0; r < 4; ++r) {
            int k = kl + r * 16;
            f32x4 v = *(const f32x4*)(src + (size_t)(kb + k) * N + nb + nl4);
            tile[nl4 + 0][k] = (ushort_t)f2bf(v[0]);
            tile[nl4 + 1][k] = (ushort_t)f2bf(v[1]);
            tile[nl4 + 2][k] = (ushort_t)f2bf(v[2]);
            tile[nl4 + 3][k] = (ushort_t)f2bf(v[3]);
        }
    }
    __syncthreads();
    {
        int nl = tid >> 2;            // 0..63 local n
        int c  = (tid & 3) * 16;      // local k chunk of 16
        int n  = nb + nl;
        int k0 = kb + c;
        bf16x4 v0 = *(const bf16x4*)&tile[nl][c + 0];
        bf16x4 v1 = *(const bf16x4*)&tile[nl][c + 4];
        bf16x4 v2 = *(const bf16x4*)&tile[nl][c + 8];
        bf16x4 v3 = *(const bf16x4*)&tile[nl][c + 12];
        ushort_t* dg = dst + ((size_t)(n >> 4) * (K / 8) + (k0 >> 3)) * 128
                           + (n & 15) * 8;
        *(bf16x4*)(dg + 0)   = v0;
        *(bf16x4*)(dg + 4)   = v1;
        *(bf16x4*)(dg + 128) = v2;
        *(bf16x4*)(dg + 132) = v3;
    }
}

// ---------------------------------------------------------------------------
// One layer of the fused MLP. H_in lives in lds (packed+swizzled, 32 x K
// bf16); W streams global->VGPR (depth-2 prefetch); acc in registers for the
// whole K-loop (NO barriers inside); then barrier -> overwrite lds with H_out
// (packed for the next layer) -> barrier.  SWAPPED mfma: D = Wfrag x Hfrag,
// so D's lane&15 = row index -> vectorized b64 H-writes.
//   K     : contraction dim;  NNOUT: next layer's K (H_out width)
//   NFPW  : 16-col W-frags per wave (8 -> N=1024 over 8 waves; 2 -> N=256)
//   FINAL : write fp32 to global (scattered via sidx) instead of LDS
// ---------------------------------------------------------------------------
template<int K, int NNOUT, int NFPW, int FINAL>
__device__ __forceinline__ void run_layer(
    char* __restrict__ lds,
    const ushort_t* __restrict__ Wt,      // task's packed weights [N][K]
    const float* __restrict__ bias,       // task's bias [N]
    float* __restrict__ outp,
    const int* __restrict__ sidx,
    int rowbase, int rowend, int lane, int wid)
{
    constexpr int NS = K / 32;
    const int loff  = (lane >> 4) * 256 + (lane & 15) * 16;
    const int nbase = wid * NFPW * 16;

    const char* wp[NFPW];
    #pragma unroll
    for (int nf = 0; nf < NFPW; ++nf)
        wp[nf] = (const char*)Wt
               + ((size_t)(nbase / 16 + nf) * (K / 8)) * 256 + loff;

    f32x4 acc[2][NFPW];
    #pragma unroll
    for (int mf = 0; mf < 2; ++mf)
        #pragma unroll
        for (int nf = 0; nf < NFPW; ++nf)
            acc[mf][nf] = (f32x4){0.f, 0.f, 0.f, 0.f};

    bf16x8 wreg[2][NFPW];
    #pragma unroll
    for (int nf = 0; nf < NFPW; ++nf)
        wreg[0][nf] = *(const bf16x8*)(wp[nf]);

    #pragma unroll
    for (int s = 0; s < NS; ++s) {
        const int cur = s & 1;
        if (s + 1 < NS) {
            #pragma unroll
            for (int nf = 0; nf < NFPW; ++nf)
                wreg[cur ^ 1][nf] =
                    *(const bf16x8*)(wp[nf] + (size_t)(s + 1) * 1024);
        }
        bf16x8 h[2];
        const int kg = s * 4 + (lane >> 4);
        #pragma unroll
        for (int mf = 0; mf < 2; ++mf)
            h[mf] = *(const bf16x8*)(lds
                        + ((size_t)(mf * (K / 8) + kg) * 256)
                        + (((lane & 15) ^ (kg & 7)) * 16));
        __builtin_amdgcn_s_setprio(1);
        #pragma unroll
        for (int mf = 0; mf < 2; ++mf)
            #pragma unroll
            for (int nf = 0; nf < NFPW; ++nf)
                acc[mf][nf] = __builtin_amdgcn_mfma_f32_16x16x32_bf16(
                    wreg[cur][nf], h[mf], acc[mf][nf], 0, 0, 0);
        __builtin_amdgcn_s_setprio(0);
    }

    const int q   = lane >> 4;
    const int m15 = lane & 15;

    if (!FINAL) {
        __syncthreads();   // all waves done reading H_in
        #pragma unroll
        for (int mf = 0; mf < 2; ++mf) {
            #pragma unroll
            for (int nf = 0; nf < NFPW; ++nf) {
                const int n_lo = nbase + nf * 16 + q * 4;
                const f32x4 bb = *(const f32x4*)(bias + n_lo);
                bf16x4 pk;
                #pragma unroll
                for (int r = 0; r < 4; ++r)
                    pk[r] = f2bf(fast_tanh(acc[mf][nf][r] + bb[r]));
                const int kg2 = n_lo >> 3;
                size_t off = ((size_t)(mf * (NNOUT / 8) + kg2) * 256)
                           + ((m15 ^ (kg2 & 7)) * 16) + (n_lo & 7) * 2;
                *(bf16x4*)(lds + off) = pk;
            }
        }
        __syncthreads();   // H_out complete
    } else {
        #pragma unroll
        for (int mf = 0; mf < 2; ++mf) {
            const int grow = rowbase + mf * 16 + m15;
            if (grow < rowend) {
                const int orow = sidx[grow];
                #pragma unroll
                for (int nf = 0; nf < NFPW; ++nf) {
                    const int n_lo = nbase + nf * 16 + q * 4;
                    const f32x4 bb = *(const f32x4*)(bias + n_lo);
                    f32x4 v;
                    #pragma unroll
                    for (int r = 0; r < 4; ++r)
                        v[r] = acc[mf][nf][r] + bb[r];
                    *(f32x4*)(outp + (size_t)orow * 256 + n_lo) = v;
                }
            }
        }
    }
}

// ---------------------------------------------------------------------------
// Fused 3-layer MLP: one 512-thread block per 32-row tile. LDS = 64 KB,
// holding x (as bf16) then H0 then H1, each overwritten in place between
// barriers. XCD-bijective tile mapping: each XCD gets a contiguous ~34-tile
// (~2-task) range so weight panels stay L2-local.
// ---------------------------------------------------------------------------
__global__ __launch_bounds__(512, 2) void fused_mlp(
    const float* __restrict__ x,
    const ushort_t* __restrict__ Wt0,
    const ushort_t* __restrict__ Wt1,
    const ushort_t* __restrict__ Wt2,
    const float* __restrict__ b0,
    const float* __restrict__ b1,
    const float* __restrict__ b2,
    float* __restrict__ out,
    const int* __restrict__ sidx,
    const int* __restrict__ tile_base,
    const int* __restrict__ tile_task,
    const int* __restrict__ tile_end,
    const int* __restrict__ ntiles)
{
    __shared__ __align__(16) char lds[65536];

    const int b    = blockIdx.x;
    const int tile = (b & 7) * (NB_FUSED / 8) + (b >> 3);  // bijective, 272=8*34
    if (tile >= *ntiles) return;
    const int rowbase = tile_base[tile];
    const int task    = tile_task[tile];
    const int rowend  = tile_end[tile];

    const int tid  = threadIdx.x;
    const int lane = tid & 63;
    const int wid  = tid >> 6;

    // ---- gather + convert x tile (32 rows x 512 fp32) into packed LDS ----
    #pragma unroll
    for (int i = 0; i < 4; ++i) {
        const int row = wid + i * 8;
        const int src = sidx[rowbase + row];
        const float* sp = x + (size_t)src * 512 + lane * 8;
        f32x4 v0 = *(const f32x4*)sp;
        f32x4 v1 = *(const f32x4*)(sp + 4);
        bf16x8 pk;
        pk[0] = f2bf(v0[0]); pk[1] = f2bf(v0[1]);
        pk[2] = f2bf(v0[2]); pk[3] = f2bf(v0[3]);
        pk[4] = f2bf(v1[0]); pk[5] = f2bf(v1[1]);
        pk[6] = f2bf(v1[2]); pk[7] = f2bf(v1[3]);
        size_t off = ((size_t)((row >> 4) * 64 + lane) * 256)
                   + (((row & 15) ^ (lane & 7)) * 16);
        *(bf16x8*)(lds + off) = pk;
    }
    __syncthreads();

    run_layer< 512, 1024, 8, 0>(lds, Wt0 + (size_t)task * 512 * 1024,
                                b0 + task * 1024, nullptr, sidx,
                                rowbase, rowend, lane, wid);
    run_layer<1024, 1024, 8, 0>(lds, Wt1 + (size_t)task * 1024 * 1024,
                                b1 + task * 1024, nullptr, sidx,
                                rowbase, rowend, lane, wid);
    run_layer<1024,  256, 2, 1>(lds, Wt2 + (size_t)task * 1024 * 256,
                                b2 + task * 256, out, sidx,
                                rowbase, rowend, lane, wid);
}

// ---------------------------------------------------------------------------
extern "C" void kernel_launch(void* const* d_in, const int* in_sizes, int n_in,
                              void* d_out, int out_size, void* d_ws, size_t ws_size,
                              hipStream_t stream)
{
    const float* x        = (const float*)d_in[0];
    const int*   task_ids = (const int*)  d_in[1];
    const float* k0       = (const float*)d_in[2];
    const float* b0       = (const float*)d_in[3];
    const float* k1       = (const float*)d_in[4];
    const float* b1       = (const float*)d_in[5];
    const float* k2       = (const float*)d_in[6];
    const float* b2       = (const float*)d_in[7];
    float* out = (float*)d_out;

    char* ws = (char*)d_ws;
    int* sidx      = (int*)ws;                    // P_ROWS ints
    int* tile_base = sidx + P_ROWS;
    int* tile_task = tile_base + 512;
    int* tile_end  = tile_task + 512;
    int* ntiles    = tile_end + 512;

    size_t off = 131072;
    ushort_t* Wt0 = (ushort_t*)(ws + off); off += (size_t)16 * 512 * 1024 * 2;
    ushort_t* Wt1 = (ushort_t*)(ws + off); off += (size_t)16 * 1024 * 1024 * 2;
    ushort_t* Wt2 = (ushort_t*)(ws + off); off += (size_t)16 * 1024 * 256 * 2;

    bucket_kernel<<<1, 256, 0, stream>>>(task_ids, sidx, tile_base, tile_task,
                                         tile_end, ntiles);
    wconv< 512, 1024><<<dim3(16,  8, 16), 256, 0, stream>>>(k0, Wt0);
    wconv<1024, 1024><<<dim3(16, 16, 16), 256, 0, stream>>>(k1, Wt1);
    wconv<1024,  256><<<dim3( 4, 16, 16), 256, 0, stream>>>(k2, Wt2);

    fused_mlp<<<NB_FUSED, 512, 0, stream>>>(
        x, Wt0, Wt1, Wt2, b0, b1, b2, out,
        sidx, tile_base, tile_task, tile_end, ntiles);
}

// Round 8
// 108.685 us; speedup vs baseline: 1.7986x; 1.3434x over previous
//
#include <hip/hip_runtime.h>
#include <math.h>

#define NUM_TASKS 16
#define B_ROWS    8192
#define TROWS     48               // rows per fused tile (3 x 16)
#define NB_FUSED  186              // max tiles: floor(8192/48) + 16
#define P_ROWS    8960             // padded sorted-row space (tasks 48-aligned)

typedef __attribute__((ext_vector_type(4))) float f32x4;
typedef __attribute__((ext_vector_type(8))) short bf16x8;
typedef __attribute__((ext_vector_type(4))) short bf16x4;
typedef unsigned short ushort_t;

__device__ __forceinline__ short f2bf(float f) {
    union { float f; unsigned u; } c; c.f = f;
    unsigned u = c.u;
    unsigned r = (u + 0x7FFFu + ((u >> 16) & 1u)) >> 16;
    return (short)r;
}

__device__ __forceinline__ float fast_tanh(float x) {
    float e = __expf(2.0f * x);
    return 1.0f - 2.0f / (e + 1.0f);
}

// ---------------------------------------------------------------------------
// Packed fragment-major layout for all operands ([X][K], 16-row groups):
//   elem(x,k;K) -> ((x>>4)*(K/8) + (k>>3))*256B + ((x&15) ^ ((k>>3)&7))*16B
//                  + (k&7)*2B            (XOR slot swizzle in LDS and global)
// A wave's 16x32 MFMA fragment = 1KB; lane l reads 16B at (l>>4)*256 +
// slot(l&15)^kg. Conflict-free read and write.
// ---------------------------------------------------------------------------

// ---------------------------------------------------------------------------
// Bucket kernel: stable counting sort of rows by task, tasks padded to 48.
// ---------------------------------------------------------------------------
__global__ __launch_bounds__(256) void bucket_kernel(
    const int* __restrict__ task_ids,
    int* __restrict__ sidx,
    int* __restrict__ tile_base,
    int* __restrict__ tile_task,
    int* __restrict__ tile_end,
    int* __restrict__ ntiles)
{
    __shared__ int cnt[256][NUM_TASKS];
    __shared__ int pstart[NUM_TASKS];
    __shared__ int tot[NUM_TASKS];

    const int tid = threadIdx.x;
    #pragma unroll
    for (int t = 0; t < NUM_TASKS; ++t) cnt[tid][t] = 0;
    const int base = tid * (B_ROWS / 256);

    for (int i = 0; i < B_ROWS / 256; ++i) {
        int t = task_ids[base + i];
        cnt[tid][t]++;
    }
    __syncthreads();

    if (tid < NUM_TASKS) {
        int s = 0;
        for (int c = 0; c < 256; ++c) { int v = cnt[c][tid]; cnt[c][tid] = s; s += v; }
        tot[tid] = s;
    }
    __syncthreads();

    if (tid == 0) {
        int p = 0, nt = 0;
        for (int t = 0; t < NUM_TASKS; ++t) {
            pstart[t] = p;
            for (int r = 0; r < tot[t]; r += TROWS) {
                tile_base[nt] = p + r;
                tile_task[nt] = t;
                tile_end[nt]  = p + tot[t];
                nt++;
            }
            p += ((tot[t] + TROWS - 1) / TROWS) * TROWS;
        }
        *ntiles = nt;
    }
    __syncthreads();

    for (int i = 0; i < P_ROWS / 256; ++i) sidx[tid + i * 256] = 0;
    __syncthreads();

    for (int i = 0; i < B_ROWS / 256; ++i) {
        int row = base + i;
        int t = task_ids[row];
        int pos = pstart[t] + cnt[tid][t];
        cnt[tid][t] = cnt[tid][t] + 1;
        sidx[pos] = row;
    }
}

// ---------------------------------------------------------------------------
// Weight convert + transpose + pack: W[t][k][n] fp32 -> packed [t][n][k] bf16.
// ---------------------------------------------------------------------------
template<int K, int N>
__global__ __launch_bounds__(256) void wconv(
    const float* __restrict__ W, ushort_t* __restrict__ Wt)
{
    const int t  = blockIdx.z;
    const int kb = blockIdx.y * 64;
    const int nb = blockIdx.x * 64;
    const float* src = W + (size_t)t * K * N;
    ushort_t* dst = Wt + (size_t)t * N * K;

    __shared__ ushort_t tile[64][68];

    const int tid = threadIdx.x;
    {
        int kl  = tid >> 4;
        int nl4 = (tid & 15) * 4;
        #pragma unroll
        for (int r = 0; r < 4; ++r) {
            int k = kl + r * 16;
            f32x4 v = *(const f32x4*)(src + (size_t)(kb + k) * N + nb + nl4);
            tile[nl4 + 0][k] = (ushort_t)f2bf(v[0]);
            tile[nl4 + 1][k] = (ushort_t)f2bf(v[1]);
            tile[nl4 + 2][k] = (ushort_t)f2bf(v[2]);
            tile[nl4 + 3][k] = (ushort_t)f2bf(v[3]);
        }
    }
    __syncthreads();
    {
        int nl = tid >> 2;            // 0..63 local n
        int c  = (tid & 3) * 16;      // local k chunk of 16
        int n  = nb + nl;
        int k0 = kb + c;
        bf16x4 v0 = *(const bf16x4*)&tile[nl][c + 0];
        bf16x4 v1 = *(const bf16x4*)&tile[nl][c + 4];
        bf16x4 v2 = *(const bf16x4*)&tile[nl][c + 8];
        bf16x4 v3 = *(const bf16x4*)&tile[nl][c + 12];
        ushort_t* dg = dst + ((size_t)(n >> 4) * (K / 8) + (k0 >> 3)) * 128
                           + (n & 15) * 8;
        *(bf16x4*)(dg + 0)   = v0;
        *(bf16x4*)(dg + 4)   = v1;
        *(bf16x4*)(dg + 128) = v2;
        *(bf16x4*)(dg + 132) = v3;
    }
}

// ---------------------------------------------------------------------------
// One fused-MLP layer. H_in in LDS (packed+XOR-swizzled, 48 x K bf16);
// W streams global->VGPR depth-2; acc registers across whole K-loop, NO
// barriers inside. Swapped mfma D = W x H -> D's lane&15 = row.
//   K: contraction; NNOUT: next layer's K; NFPW: 16-col W frags per wave;
//   INPLACE: barrier before overwriting H_in; FINAL: fp32 scatter to out.
// Per wave: 3 m-frags x NFPW n-frags.
// ---------------------------------------------------------------------------
template<int K, int NNOUT, int NFPW, int INPLACE, int FINAL>
__device__ __forceinline__ void run_layer(
    const char* __restrict__ Hin,
    char* __restrict__ Hout,
    const ushort_t* __restrict__ Wt,      // task's packed weights [N][K]
    const float* __restrict__ bias,       // task's bias
    float* __restrict__ outp,
    const int* __restrict__ sidx,
    int rowbase, int rowend, int lane, int wid)
{
    constexpr int NS = K / 32;
    const int loff  = (lane >> 4) * 256 + (lane & 15) * 16;
    const int nbase = wid * NFPW * 16;

    const char* wp[NFPW];
    #pragma unroll
    for (int nf = 0; nf < NFPW; ++nf)
        wp[nf] = (const char*)Wt
               + ((size_t)(nbase / 16 + nf) * (K / 8)) * 256 + loff;

    f32x4 acc[3][NFPW];
    #pragma unroll
    for (int mf = 0; mf < 3; ++mf)
        #pragma unroll
        for (int nf = 0; nf < NFPW; ++nf)
            acc[mf][nf] = (f32x4){0.f, 0.f, 0.f, 0.f};

    bf16x8 wreg[2][NFPW];
    #pragma unroll
    for (int nf = 0; nf < NFPW; ++nf)
        wreg[0][nf] = *(const bf16x8*)(wp[nf]);

    #pragma unroll
    for (int s = 0; s < NS; ++s) {
        const int cur = s & 1;
        if (s + 1 < NS) {
            #pragma unroll
            for (int nf = 0; nf < NFPW; ++nf)
                wreg[cur ^ 1][nf] =
                    *(const bf16x8*)(wp[nf] + (size_t)(s + 1) * 1024);
        }
        bf16x8 h[3];
        const int kg = s * 4 + (lane >> 4);
        #pragma unroll
        for (int mf = 0; mf < 3; ++mf)
            h[mf] = *(const bf16x8*)(Hin
                        + ((size_t)(mf * (K / 8) + kg) * 256)
                        + (((lane & 15) ^ (kg & 7)) * 16));
        __builtin_amdgcn_s_setprio(1);
        #pragma unroll
        for (int mf = 0; mf < 3; ++mf)
            #pragma unroll
            for (int nf = 0; nf < NFPW; ++nf)
                acc[mf][nf] = __builtin_amdgcn_mfma_f32_16x16x32_bf16(
                    wreg[cur][nf], h[mf], acc[mf][nf], 0, 0, 0);
        __builtin_amdgcn_s_setprio(0);
    }

    const int q   = lane >> 4;
    const int m15 = lane & 15;

    if (!FINAL) {
        if (INPLACE) __syncthreads();     // all waves done reading H_in
        #pragma unroll
        for (int mf = 0; mf < 3; ++mf) {
            #pragma unroll
            for (int nf = 0; nf < NFPW; ++nf) {
                const int n_lo = nbase + nf * 16 + q * 4;
                const f32x4 bb = *(const f32x4*)(bias + n_lo);
                bf16x4 pk;
                #pragma unroll
                for (int r = 0; r < 4; ++r)
                    pk[r] = f2bf(fast_tanh(acc[mf][nf][r] + bb[r]));
                const int kg2 = n_lo >> 3;
                size_t off = ((size_t)(mf * (NNOUT / 8) + kg2) * 256)
                           + ((m15 ^ (kg2 & 7)) * 16) + (n_lo & 7) * 2;
                *(bf16x4*)(Hout + off) = pk;
            }
        }
        __syncthreads();                  // H_out complete
    } else {
        #pragma unroll
        for (int mf = 0; mf < 3; ++mf) {
            const int grow = rowbase + mf * 16 + m15;
            if (grow < rowend) {
                const int orow = sidx[grow];
                #pragma unroll
                for (int nf = 0; nf < NFPW; ++nf) {
                    const int n_lo = nbase + nf * 16 + q * 4;
                    const f32x4 bb = *(const f32x4*)(bias + n_lo);
                    f32x4 v;
                    #pragma unroll
                    for (int r = 0; r < 4; ++r)
                        v[r] = acc[mf][nf][r] + bb[r];
                    *(f32x4*)(outp + (size_t)orow * 256 + n_lo) = v;
                }
            }
        }
    }
}

// ---------------------------------------------------------------------------
// Fused 3-layer MLP: one 512-thread block per 48-row tile.
// LDS 144 KB: H region 96 KB (48x1024 bf16 packed) + x region 48 KB.
// __launch_bounds__(512,1): 256-VGPR budget -> real depth-2 W prefetch.
// 4 barriers per tile total; none inside any K-loop.
// ---------------------------------------------------------------------------
__global__ __launch_bounds__(512, 1) void fused_mlp(
    const float* __restrict__ x,
    const ushort_t* __restrict__ Wt0,
    const ushort_t* __restrict__ Wt1,
    const ushort_t* __restrict__ Wt2,
    const float* __restrict__ b0,
    const float* __restrict__ b1,
    const float* __restrict__ b2,
    float* __restrict__ out,
    const int* __restrict__ sidx,
    const int* __restrict__ tile_base,
    const int* __restrict__ tile_task,
    const int* __restrict__ tile_end,
    const int* __restrict__ ntiles)
{
    __shared__ __align__(16) char lds[147456];
    char* Hreg = lds;            // 96 KB
    char* Xreg = lds + 98304;    // 48 KB

    // bijective XCD mapping (m204): contiguous ~23-tile (≈2-task) chunk/XCD
    const int orig = blockIdx.x;
    constexpr int q8 = NB_FUSED / 8, r8 = NB_FUSED % 8;
    const int xcd = orig & 7, idx = orig >> 3;
    const int tile = (xcd < r8 ? xcd * (q8 + 1) : r8 * (q8 + 1) + (xcd - r8) * q8) + idx;

    if (tile >= *ntiles) return;
    const int rowbase = tile_base[tile];
    const int task    = tile_task[tile];
    const int rowend  = tile_end[tile];

    const int tid  = threadIdx.x;
    const int lane = tid & 63;
    const int wid  = tid >> 6;

    // ---- gather + convert x tile (48 rows x 512 fp32) into packed LDS ----
    #pragma unroll
    for (int i = 0; i < 6; ++i) {
        const int row = wid + i * 8;
        const int src = sidx[rowbase + row];
        const float* sp = x + (size_t)src * 512 + lane * 8;
        f32x4 v0 = *(const f32x4*)sp;
        f32x4 v1 = *(const f32x4*)(sp + 4);
        bf16x8 pk;
        pk[0] = f2bf(v0[0]); pk[1] = f2bf(v0[1]);
        pk[2] = f2bf(v0[2]); pk[3] = f2bf(v0[3]);
        pk[4] = f2bf(v1[0]); pk[5] = f2bf(v1[1]);
        pk[6] = f2bf(v1[2]); pk[7] = f2bf(v1[3]);
        size_t off = ((size_t)((row >> 4) * 64 + lane) * 256)
                   + (((row & 15) ^ (lane & 7)) * 16);
        *(bf16x8*)(Xreg + off) = pk;
    }
    __syncthreads();

    run_layer< 512, 1024, 8, 0, 0>(Xreg, Hreg,
                                   Wt0 + (size_t)task * 512 * 1024,
                                   b0 + task * 1024, nullptr, sidx,
                                   rowbase, rowend, lane, wid);
    run_layer<1024, 1024, 8, 1, 0>(Hreg, Hreg,
                                   Wt1 + (size_t)task * 1024 * 1024,
                                   b1 + task * 1024, nullptr, sidx,
                                   rowbase, rowend, lane, wid);
    run_layer<1024,  256, 2, 0, 1>(Hreg, nullptr,
                                   Wt2 + (size_t)task * 1024 * 256,
                                   b2 + task * 256, out, sidx,
                                   rowbase, rowend, lane, wid);
}

// ---------------------------------------------------------------------------
extern "C" void kernel_launch(void* const* d_in, const int* in_sizes, int n_in,
                              void* d_out, int out_size, void* d_ws, size_t ws_size,
                              hipStream_t stream)
{
    const float* x        = (const float*)d_in[0];
    const int*   task_ids = (const int*)  d_in[1];
    const float* k0       = (const float*)d_in[2];
    const float* b0       = (const float*)d_in[3];
    const float* k1       = (const float*)d_in[4];
    const float* b1       = (const float*)d_in[5];
    const float* k2       = (const float*)d_in[6];
    const float* b2       = (const float*)d_in[7];
    float* out = (float*)d_out;

    char* ws = (char*)d_ws;
    int* sidx      = (int*)ws;                    // P_ROWS ints
    int* tile_base = sidx + P_ROWS;
    int* tile_task = tile_base + 512;
    int* tile_end  = tile_task + 512;
    int* ntiles    = tile_end + 512;

    size_t off = 131072;
    ushort_t* Wt0 = (ushort_t*)(ws + off); off += (size_t)16 * 512 * 1024 * 2;
    ushort_t* Wt1 = (ushort_t*)(ws + off); off += (size_t)16 * 1024 * 1024 * 2;
    ushort_t* Wt2 = (ushort_t*)(ws + off); off += (size_t)16 * 1024 * 256 * 2;

    bucket_kernel<<<1, 256, 0, stream>>>(task_ids, sidx, tile_base, tile_task,
                                         tile_end, ntiles);
    wconv< 512, 1024><<<dim3(16,  8, 16), 256, 0, stream>>>(k0, Wt0);
    wconv<1024, 1024><<<dim3(16, 16, 16), 256, 0, stream>>>(k1, Wt1);
    wconv<1024,  256><<<dim3( 4, 16, 16), 256, 0, stream>>>(k2, Wt2);

    fused_mlp<<<NB_FUSED, 512, 0, stream>>>(
        x, Wt0, Wt1, Wt2, b0, b1, b2, out,
        sidx, tile_base, tile_task, tile_end, ntiles);
}